// Round 12
// baseline (189.527 us; speedup 1.0000x reference)
//
#include <hip/hip_runtime.h>
#include <stdint.h>

#define NH     16
#define LSEQ   2048
#define DH     64
#define HDIM   1024
#define BATCH  2

typedef __attribute__((ext_vector_type(8))) short bf16x8;
typedef __attribute__((ext_vector_type(8))) unsigned short u16x8;
typedef __attribute__((ext_vector_type(4))) float f32x4;
typedef __attribute__((ext_vector_type(16))) float f32x16;

// fp32 -> bf16 (RNE)
static __device__ inline unsigned short f2bs(float f) {
    union { float f; uint32_t u; } v; v.f = f;
    uint32_t u = v.u;
    return (unsigned short)((u + 0x7FFFu + ((u >> 16) & 1u)) >> 16);
}

static __device__ inline unsigned int cvtpk(float lo, float hi) {
    unsigned int r;
    asm("v_cvt_pk_bf16_f32 %0, %1, %2" : "=v"(r) : "v"(lo), "v"(hi));
    return r;
}
static __device__ inline void pl32swap(unsigned int &a, unsigned int &b) {
    asm volatile("v_permlane32_swap_b32 %0, %1" : "+v"(a), "+v"(b));
}

#define GLOAD_LDS(gp, lp) \
    __builtin_amdgcn_global_load_lds((const __attribute__((address_space(1))) void*)(gp), \
                                     (__attribute__((address_space(3))) void*)(lp), 16, 0, 0)

#define MFMA32(A, B, C) __builtin_amdgcn_mfma_f32_32x32x16_bf16((A), (B), (C), 0, 0, 0)

// sqrt(0.125 * log2(e)) — folded into xb so (sQ)·(sK) carries the softmax scale
#define QK_SCALE 0.42466083f

// ---------------------------------------------------------------------------
// Kernel 1: prep (unchanged from r17 — verified frag-major layouts).
// ---------------------------------------------------------------------------
__global__ __launch_bounds__(256) void prep_kernel(const float* __restrict__ x,
                                                   const float* __restrict__ W,
                                                   unsigned short* __restrict__ xb,
                                                   unsigned short* __restrict__ xt,
                                                   unsigned short* __restrict__ wbt) {
    const int lt = blockIdx.x, bh = blockIdx.y;
    const int bid = bh * 32 + lt;
    const int t = threadIdx.x;

    if (t < 128) {
        const int gid = bid * 128 + t;
        const int n  = gid >> 7;
        const int kc = gid & 127;
        const float* src = W + (size_t)n * 1024 + kc * 8;
        float4 f0 = *(const float4*)(src);
        float4 f1 = *(const float4*)(src + 4);
        u16x8 v;
        v[0]=f2bs(f0.x); v[1]=f2bs(f0.y); v[2]=f2bs(f0.z); v[3]=f2bs(f0.w);
        v[4]=f2bs(f1.x); v[5]=f2bs(f1.y); v[6]=f2bs(f1.z); v[7]=f2bs(f1.w);
        const int nt = n >> 7, rn = n & 127;
        const int kt = kc >> 3, c = kc & 7;
        *(u16x8*)(wbt + (((size_t)nt * 16 + kt) * 128 + rn) * 64 + ((c ^ (rn & 7)) * 8)) = v;
    }

    const int b = bh >> 4, h = bh & 15;
    const int r = t >> 2, cp = t & 3;

    __shared__ __align__(16) unsigned short Sm[64][72];

    const float* src = x + ((size_t)(b * LSEQ + lt * 64 + r)) * HDIM + h * DH + cp * 16;
    float4 f0 = *(const float4*)(src);
    float4 f1 = *(const float4*)(src + 4);
    float4 f2 = *(const float4*)(src + 8);
    float4 f3 = *(const float4*)(src + 12);
    u16x8 lo, hi;
    lo[0]=f2bs(f0.x); lo[1]=f2bs(f0.y); lo[2]=f2bs(f0.z); lo[3]=f2bs(f0.w);
    lo[4]=f2bs(f1.x); lo[5]=f2bs(f1.y); lo[6]=f2bs(f1.z); lo[7]=f2bs(f1.w);
    hi[0]=f2bs(f2.x); hi[1]=f2bs(f2.y); hi[2]=f2bs(f2.z); hi[3]=f2bs(f2.w);
    hi[4]=f2bs(f3.x); hi[5]=f2bs(f3.y); hi[6]=f2bs(f3.z); hi[7]=f2bs(f3.w);
    u16x8 slo, shi;
    slo[0]=f2bs(f0.x*QK_SCALE); slo[1]=f2bs(f0.y*QK_SCALE); slo[2]=f2bs(f0.z*QK_SCALE); slo[3]=f2bs(f0.w*QK_SCALE);
    slo[4]=f2bs(f1.x*QK_SCALE); slo[5]=f2bs(f1.y*QK_SCALE); slo[6]=f2bs(f1.z*QK_SCALE); slo[7]=f2bs(f1.w*QK_SCALE);
    shi[0]=f2bs(f2.x*QK_SCALE); shi[1]=f2bs(f2.y*QK_SCALE); shi[2]=f2bs(f2.z*QK_SCALE); shi[3]=f2bs(f2.w*QK_SCALE);
    shi[4]=f2bs(f3.x*QK_SCALE); shi[5]=f2bs(f3.y*QK_SCALE); shi[6]=f2bs(f3.z*QK_SCALE); shi[7]=f2bs(f3.w*QK_SCALE);

    {   // xb frag-major: st = lt*2 + (r>>5); ds = cp; lane = hh*32 + (r&31)
        unsigned short* xbase = xb + (size_t)bh * 131072
                              + ((size_t)lt * 2 + (r >> 5)) * 2048 + cp * 512 + (r & 31) * 8;
        *(u16x8*)(xbase)       = slo;   // hh=0 (d = cp*16 + 0..7)
        *(u16x8*)(xbase + 256) = shi;   // hh=1 (d = cp*16 + 8..15)
    }
    *(u16x8*)&Sm[r][cp * 16]     = lo;
    *(u16x8*)&Sm[r][cp * 16 + 8] = hi;
    __syncthreads();

    {   // xt frag-major: tile = lt; side = d>>5; ks = part>>4; lane = hh*32 + (d&31)
        const int d = t >> 2, part = (t & 3) * 16;
        unsigned short* vbase = xt + (size_t)bh * 131072 + (size_t)lt * 4096
                              + (d >> 5) * 2048 + (part >> 4) * 512 + (d & 31) * 8;
        u16x8 g0, g1;
        #pragma unroll
        for (int i = 0; i < 8; ++i) g0[i] = Sm[part + i][d];
        #pragma unroll
        for (int i = 0; i < 8; ++i) g1[i] = Sm[part + 8 + i][d];
        *(u16x8*)(vbase)       = g0;   // kv part..part+7   (hh=0)
        *(u16x8*)(vbase + 256) = g1;   // kv part+8..part+15 (hh=1)
    }
}

// ---------------------------------------------------------------------------
// Kernel 2: flash attention, 32x32 MFMA, zero-LDS main loop.
// r19 TLP probe: KV-SPLIT x2. Block = 512 thr = 8 waves; waves 0-3 process
// KV tiles 0-15, waves 4-7 tiles 16-31, same 4 q-subtiles. Total waves
// 2048 -> 4096 => 4 waves/SIMD (was 2 — the one axis never probed).
// Combine: upper waves write accA/accB/accS to LDS (lane-major, conflict-
// free), one barrier, lower waves add + normalize + store (r17 epilogue).
// grid (32 bh, 16 qt) = 512 blocks x 512 thr.
// ---------------------------------------------------------------------------
__global__ __launch_bounds__(512, 4) void attn_kernel(const unsigned short* __restrict__ xb,
                                                      const unsigned short* __restrict__ xt,
                                                      unsigned short* __restrict__ ctxt) {
    const int bh = blockIdx.x;
    const int qt = blockIdx.y;
    const int tid = threadIdx.x;
    const int w = tid >> 6;          // 0..7
    const int half = w >> 2;         // KV half
    const int wq = w & 3;            // q-subtile
    const int lane = tid & 63;
    const int l31 = lane & 31, hh = lane >> 5;

    // combine buffer: [wq][acc(3)][chunk(4)][lane][4 f32] = 48 KB
    __shared__ __align__(16) float cmb[12288];

    const char* xbB = (const char*)(xb + (size_t)bh * 131072);
    const char* xtB = (const char*)(xt + (size_t)bh * 131072);

    // --- Q hoist: B-frags for q-subtile st_q = qt*4 + wq ---
    bf16x8 qf[4];
    {
        const char* qbase = xbB + (size_t)(qt * 4 + wq) * 4096 + lane * 16;
        #pragma unroll
        for (int ds = 0; ds < 4; ++ds)
            qf[ds] = *(const bf16x8*)(qbase + ds * 1024);
    }

    // ones B-frag for the row-sum MFMA
    bf16x8 ones;
    #pragma unroll
    for (int i = 0; i < 8; ++i) ones[i] = (short)0x3F80;

    f32x16 accA, accB, accS;
    #pragma unroll
    for (int r = 0; r < 16; ++r) { accA[r] = 0.f; accB[r] = 0.f; accS[r] = 0.f; }

    const char* ka = xbB + (size_t)half * 16 * 8192 + lane * 16;
    const char* va = xtB + (size_t)half * 16 * 8192 + lane * 16;

    for (int it = 0; it < 16; ++it) {
        // --- K frags direct to registers ---
        bf16x8 kfa[4], kfb[4];
        #pragma unroll
        for (int ds = 0; ds < 4; ++ds) {
            kfa[ds] = *(const bf16x8*)(ka + ds * 1024);
            kfb[ds] = *(const bf16x8*)(ka + 4096 + ds * 1024);
        }

        // --- QK: S^T[kv][q], two 32-kv subtiles ---
        f32x16 s0, s1;
        #pragma unroll
        for (int r = 0; r < 16; ++r) { s0[r] = 0.f; s1[r] = 0.f; }
        __builtin_amdgcn_s_setprio(1);
        #pragma unroll
        for (int ds = 0; ds < 4; ++ds) {
            s0 = MFMA32(kfa[ds], qf[ds], s0);
            s1 = MFMA32(kfb[ds], qf[ds], s1);
        }
        __builtin_amdgcn_s_setprio(0);

        // --- V frags direct to registers (latency hidden under softmax) ---
        bf16x8 vfa[4], vfb[4];
        #pragma unroll
        for (int ks = 0; ks < 4; ++ks) {
            vfa[ks] = *(const bf16x8*)(va + ks * 1024);
            vfb[ks] = *(const bf16x8*)(va + 4096 + ks * 1024);
        }
        ka += 8192;
        va += 8192;

        // --- exp2 in place (lane-local rows, scale pre-folded) ---
        #pragma unroll
        for (int r = 0; r < 16; ++r) {
            s0[r] = __builtin_amdgcn_exp2f(s0[r]);
            s1[r] = __builtin_amdgcn_exp2f(s1[r]);
        }

        // --- pack P -> A-frags via cvt_pk + permlane32_swap ---
        bf16x8 pa[4];
        #pragma unroll
        for (int ks = 0; ks < 4; ++ks) {
            const int r0 = (ks & 1) * 8;
            unsigned int x0, y0, x1, y1;
            if (ks < 2) {
                x0 = cvtpk(s0[r0 + 0], s0[r0 + 1]);
                y0 = cvtpk(s0[r0 + 4], s0[r0 + 5]);
                x1 = cvtpk(s0[r0 + 2], s0[r0 + 3]);
                y1 = cvtpk(s0[r0 + 6], s0[r0 + 7]);
            } else {
                x0 = cvtpk(s1[r0 + 0], s1[r0 + 1]);
                y0 = cvtpk(s1[r0 + 4], s1[r0 + 5]);
                x1 = cvtpk(s1[r0 + 2], s1[r0 + 3]);
                y1 = cvtpk(s1[r0 + 6], s1[r0 + 7]);
            }
            pl32swap(x0, y0);
            pl32swap(x1, y1);
            union { unsigned int u[4]; bf16x8 v; } pu;
            pu.u[0] = x0; pu.u[1] = x1; pu.u[2] = y0; pu.u[3] = y1;
            pa[ks] = pu.v;
        }

        // --- PV + row-sum on the matrix pipe ---
        __builtin_amdgcn_s_setprio(1);
        #pragma unroll
        for (int ks = 0; ks < 4; ++ks) {
            accA = MFMA32(pa[ks], vfa[ks], accA);
            accB = MFMA32(pa[ks], vfb[ks], accB);
            accS = MFMA32(pa[ks], ones, accS);
        }
        __builtin_amdgcn_s_setprio(0);
    }

    // --- combine: upper half writes partials to LDS, lower half reduces ---
    if (half) {
        float* b = cmb + (size_t)wq * 3072 + lane * 4;   // [wq][acc][g][lane][4]
        #pragma unroll
        for (int g = 0; g < 4; ++g) {
            f32x4 cA = { accA[g*4+0], accA[g*4+1], accA[g*4+2], accA[g*4+3] };
            f32x4 cB = { accB[g*4+0], accB[g*4+1], accB[g*4+2], accB[g*4+3] };
            f32x4 cS = { accS[g*4+0], accS[g*4+1], accS[g*4+2], accS[g*4+3] };
            *(f32x4*)(b +    0 + g * 256) = cA;
            *(f32x4*)(b + 1024 + g * 256) = cB;
            *(f32x4*)(b + 2048 + g * 256) = cS;
        }
    }
    __syncthreads();
    if (!half) {
        const float* b = cmb + (size_t)wq * 3072 + lane * 4;
        #pragma unroll
        for (int g = 0; g < 4; ++g) {
            f32x4 cA = *(const f32x4*)(b +    0 + g * 256);
            f32x4 cB = *(const f32x4*)(b + 1024 + g * 256);
            f32x4 cS = *(const f32x4*)(b + 2048 + g * 256);
            #pragma unroll
            for (int j = 0; j < 4; ++j) {
                accA[g*4+j] += cA[j];
                accB[g*4+j] += cB[j];
                accS[g*4+j] += cS[j];
            }
        }

        // --- epilogue: accS[r] is the rowsum for accA[r]/accB[r]'s row ---
        const int bb = bh >> 4, hd = bh & 15;
        const int mt = bb * 16 + qt;
        unsigned short* tbase = ctxt + ((size_t)mt * 16 + hd) * 128 * 64;
        const int c80 = l31 >> 3, c81 = 4 + (l31 >> 3), ce = l31 & 7;
        #pragma unroll
        for (int r = 0; r < 16; ++r) {
            const float iv = 1.0f / accS[r];
            const int crow = (r & 3) + 8 * (r >> 2) + 4 * hh;
            const int rr = wq * 32 + crow;
            unsigned short* rowp = tbase + rr * 64;
            const int sw = rr & 7;
            rowp[((c80 ^ sw) * 8) + ce] = f2bs(accA[r] * iv);
            rowp[((c81 ^ sw) * 8) + ce] = f2bs(accB[r] * iv);
        }
    }
}

// ---------------------------------------------------------------------------
// Kernel 3: out = ctx @ W^T + b (unchanged).
// ---------------------------------------------------------------------------
__global__ __launch_bounds__(256) void proj_kernel(const unsigned short* __restrict__ ctxt,
                                                   const unsigned short* __restrict__ wbt,
                                                   const float* __restrict__ bias,
                                                   float* __restrict__ out) {
    const int ntb = blockIdx.x;
    const int mtb = blockIdx.y;
    const int tid = threadIdx.x;
    const int w = tid >> 6, lane = tid & 63;
    const int la = lane & 15, quad = lane >> 4;
    const int wm = (w >> 1) * 64, wn = (w & 1) * 64;

    __shared__ __align__(16) unsigned short As[2][8192];
    __shared__ __align__(16) unsigned short Bs[2][8192];

    const unsigned short* abase = ctxt + (size_t)mtb * 16 * 8192;
    const unsigned short* bbase = wbt  + (size_t)ntb * 16 * 8192;

    const int sw0 = ((quad)     ^ (la & 7)) * 8;
    const int sw1 = ((quad + 4) ^ (la & 7)) * 8;

    const f32x4 fzero = {0.f, 0.f, 0.f, 0.f};
    f32x4 acc[4][4];
    #pragma unroll
    for (int i = 0; i < 4; ++i)
        #pragma unroll
        for (int j = 0; j < 4; ++j) acc[i][j] = fzero;

    #pragma unroll
    for (int j = 0; j < 4; ++j) {
        const int fc = j * 256 + tid;
        GLOAD_LDS((const char*)abase + fc * 16, (char*)As[0] + fc * 16);
        GLOAD_LDS((const char*)bbase + fc * 16, (char*)Bs[0] + fc * 16);
    }
    __syncthreads();

    for (int kt = 0; kt < 16; ++kt) {
        if (kt < 15) {
            const char* asrc = (const char*)(abase + (kt + 1) * 8192);
            const char* bsrc = (const char*)(bbase + (kt + 1) * 8192);
            char* adst = (char*)As[(kt + 1) & 1];
            char* bdst = (char*)Bs[(kt + 1) & 1];
            #pragma unroll
            for (int j = 0; j < 4; ++j) {
                const int fc = j * 256 + tid;
                GLOAD_LDS(asrc + fc * 16, adst + fc * 16);
                GLOAD_LDS(bsrc + fc * 16, bdst + fc * 16);
            }
        }

        const unsigned short* Ab = As[kt & 1];
        const unsigned short* Bb = Bs[kt & 1];
        #pragma unroll
        for (int ks2 = 0; ks2 < 2; ++ks2) {
            const int sw = ks2 ? sw1 : sw0;
            bf16x8 af[4], bfr[4];
            #pragma unroll
            for (int mt = 0; mt < 4; ++mt) af[mt]  = *(const bf16x8*)&Ab[(wm + mt * 16 + la) * 64 + sw];
            #pragma unroll
            for (int nt = 0; nt < 4; ++nt) bfr[nt] = *(const bf16x8*)&Bb[(wn + nt * 16 + la) * 64 + sw];
            #pragma unroll
            for (int mt = 0; mt < 4; ++mt)
                #pragma unroll
                for (int nt = 0; nt < 4; ++nt)
                    acc[mt][nt] = __builtin_amdgcn_mfma_f32_16x16x32_bf16(af[mt], bfr[nt], acc[mt][nt], 0, 0, 0);
        }
        __syncthreads();
    }

    const int m0 = mtb * 128, n0 = ntb * 128;
    #pragma unroll
    for (int nt = 0; nt < 4; ++nt) {
        const int n = n0 + wn + nt * 16 + la;
        const float bv = bias[n];
        #pragma unroll
        for (int mt = 0; mt < 4; ++mt)
            #pragma unroll
            for (int r = 0; r < 4; ++r) {
                const int m = m0 + wm + mt * 16 + quad * 4 + r;
                out[(size_t)m * HDIM + n] = acc[mt][nt][r] + bv;
            }
    }
}

// ---------------------------------------------------------------------------
extern "C" void kernel_launch(void* const* d_in, const int* in_sizes, int n_in,
                              void* d_out, int out_size, void* d_ws, size_t ws_size,
                              hipStream_t stream) {
    const float* x    = (const float*)d_in[0];
    const float* W    = (const float*)d_in[1];
    const float* bias = (const float*)d_in[2];
    float* out = (float*)d_out;

    // ws layout (bytes): ctxt 8M | xb 8M | xt 8M | wbt 2M
    unsigned short* ctxt = (unsigned short*)d_ws;
    unsigned short* xbp  = (unsigned short*)((char*)d_ws + ( 8u << 20));
    unsigned short* xtp  = (unsigned short*)((char*)d_ws + (16u << 20));
    unsigned short* wbt  = (unsigned short*)((char*)d_ws + (24u << 20));

    prep_kernel<<<dim3(32, 32), 256, 0, stream>>>(x, W, xbp, xtp, wbt);
    attn_kernel<<<dim3(32, 16), 512, 0, stream>>>(xbp, xtp, ctxt);
    proj_kernel<<<dim3(8, 32), 256, 0, stream>>>(ctxt, wbt, bias, out);
}

// Round 13
// 169.352 us; speedup vs baseline: 1.1191x; 1.1191x over previous
//
#include <hip/hip_runtime.h>
#include <stdint.h>

#define NH     16
#define LSEQ   2048
#define DH     64
#define HDIM   1024
#define BATCH  2

typedef __attribute__((ext_vector_type(8))) short bf16x8;
typedef __attribute__((ext_vector_type(8))) unsigned short u16x8;
typedef __attribute__((ext_vector_type(4))) float f32x4;
typedef __attribute__((ext_vector_type(16))) float f32x16;

// fp32 -> bf16 (RNE)
static __device__ inline unsigned short f2bs(float f) {
    union { float f; uint32_t u; } v; v.f = f;
    uint32_t u = v.u;
    return (unsigned short)((u + 0x7FFFu + ((u >> 16) & 1u)) >> 16);
}

static __device__ inline unsigned int cvtpk(float lo, float hi) {
    unsigned int r;
    asm("v_cvt_pk_bf16_f32 %0, %1, %2" : "=v"(r) : "v"(lo), "v"(hi));
    return r;
}
static __device__ inline void pl32swap(unsigned int &a, unsigned int &b) {
    asm volatile("v_permlane32_swap_b32 %0, %1" : "+v"(a), "+v"(b));
}

#define GLOAD_LDS(gp, lp) \
    __builtin_amdgcn_global_load_lds((const __attribute__((address_space(1))) void*)(gp), \
                                     (__attribute__((address_space(3))) void*)(lp), 16, 0, 0)

#define MFMA32(A, B, C) __builtin_amdgcn_mfma_f32_32x32x16_bf16((A), (B), (C), 0, 0, 0)

// sqrt(0.125 * log2(e)) — folded into xb so (sQ)·(sK) carries the softmax scale
#define QK_SCALE 0.42466083f

// ---------------------------------------------------------------------------
// Kernel 1: prep (unchanged from r17 — verified frag-major layouts).
// ---------------------------------------------------------------------------
__global__ __launch_bounds__(256) void prep_kernel(const float* __restrict__ x,
                                                   const float* __restrict__ W,
                                                   unsigned short* __restrict__ xb,
                                                   unsigned short* __restrict__ xt,
                                                   unsigned short* __restrict__ wbt) {
    const int lt = blockIdx.x, bh = blockIdx.y;
    const int bid = bh * 32 + lt;
    const int t = threadIdx.x;

    if (t < 128) {
        const int gid = bid * 128 + t;
        const int n  = gid >> 7;
        const int kc = gid & 127;
        const float* src = W + (size_t)n * 1024 + kc * 8;
        float4 f0 = *(const float4*)(src);
        float4 f1 = *(const float4*)(src + 4);
        u16x8 v;
        v[0]=f2bs(f0.x); v[1]=f2bs(f0.y); v[2]=f2bs(f0.z); v[3]=f2bs(f0.w);
        v[4]=f2bs(f1.x); v[5]=f2bs(f1.y); v[6]=f2bs(f1.z); v[7]=f2bs(f1.w);
        const int nt = n >> 7, rn = n & 127;
        const int kt = kc >> 3, c = kc & 7;
        *(u16x8*)(wbt + (((size_t)nt * 16 + kt) * 128 + rn) * 64 + ((c ^ (rn & 7)) * 8)) = v;
    }

    const int b = bh >> 4, h = bh & 15;
    const int r = t >> 2, cp = t & 3;

    __shared__ __align__(16) unsigned short Sm[64][72];

    const float* src = x + ((size_t)(b * LSEQ + lt * 64 + r)) * HDIM + h * DH + cp * 16;
    float4 f0 = *(const float4*)(src);
    float4 f1 = *(const float4*)(src + 4);
    float4 f2 = *(const float4*)(src + 8);
    float4 f3 = *(const float4*)(src + 12);
    u16x8 lo, hi;
    lo[0]=f2bs(f0.x); lo[1]=f2bs(f0.y); lo[2]=f2bs(f0.z); lo[3]=f2bs(f0.w);
    lo[4]=f2bs(f1.x); lo[5]=f2bs(f1.y); lo[6]=f2bs(f1.z); lo[7]=f2bs(f1.w);
    hi[0]=f2bs(f2.x); hi[1]=f2bs(f2.y); hi[2]=f2bs(f2.z); hi[3]=f2bs(f2.w);
    hi[4]=f2bs(f3.x); hi[5]=f2bs(f3.y); hi[6]=f2bs(f3.z); hi[7]=f2bs(f3.w);
    u16x8 slo, shi;
    slo[0]=f2bs(f0.x*QK_SCALE); slo[1]=f2bs(f0.y*QK_SCALE); slo[2]=f2bs(f0.z*QK_SCALE); slo[3]=f2bs(f0.w*QK_SCALE);
    slo[4]=f2bs(f1.x*QK_SCALE); slo[5]=f2bs(f1.y*QK_SCALE); slo[6]=f2bs(f1.z*QK_SCALE); slo[7]=f2bs(f1.w*QK_SCALE);
    shi[0]=f2bs(f2.x*QK_SCALE); shi[1]=f2bs(f2.y*QK_SCALE); shi[2]=f2bs(f2.z*QK_SCALE); shi[3]=f2bs(f2.w*QK_SCALE);
    shi[4]=f2bs(f3.x*QK_SCALE); shi[5]=f2bs(f3.y*QK_SCALE); shi[6]=f2bs(f3.z*QK_SCALE); shi[7]=f2bs(f3.w*QK_SCALE);

    {   // xb frag-major: st = lt*2 + (r>>5); ds = cp; lane = hh*32 + (r&31)
        unsigned short* xbase = xb + (size_t)bh * 131072
                              + ((size_t)lt * 2 + (r >> 5)) * 2048 + cp * 512 + (r & 31) * 8;
        *(u16x8*)(xbase)       = slo;   // hh=0 (d = cp*16 + 0..7)
        *(u16x8*)(xbase + 256) = shi;   // hh=1 (d = cp*16 + 8..15)
    }
    *(u16x8*)&Sm[r][cp * 16]     = lo;
    *(u16x8*)&Sm[r][cp * 16 + 8] = hi;
    __syncthreads();

    {   // xt frag-major: tile = lt; side = d>>5; ks = part>>4; lane = hh*32 + (d&31)
        const int d = t >> 2, part = (t & 3) * 16;
        unsigned short* vbase = xt + (size_t)bh * 131072 + (size_t)lt * 4096
                              + (d >> 5) * 2048 + (part >> 4) * 512 + (d & 31) * 8;
        u16x8 g0, g1;
        #pragma unroll
        for (int i = 0; i < 8; ++i) g0[i] = Sm[part + i][d];
        #pragma unroll
        for (int i = 0; i < 8; ++i) g1[i] = Sm[part + 8 + i][d];
        *(u16x8*)(vbase)       = g0;   // kv part..part+7   (hh=0)
        *(u16x8*)(vbase + 256) = g1;   // kv part+8..part+15 (hh=1)
    }
}

// ---------------------------------------------------------------------------
// Kernel 2: flash attention, 32x32 MFMA, zero LDS / zero barriers.
// r20 TLP probe (spill-proof): D-SPLIT. Wave (wq, dh) computes the FULL
// QK^T + softmax for its 32 q-rows (QK redundant across dh — cheap on the
// idle matrix pipe) but only its 32-of-64 d output columns: drops accB and
// half the V-frags -> working set fits 170 VGPR (launch_bounds(256,3) cap;
// r19's failure was a forced-64-VGPR scratch spill, WRITE_SIZE 8->62MB).
// Each wave owns its complete output: NO combine, no LDS, no barriers.
// grid (32 bh, 32 qp) = 1024 blocks x 256 thr = 4096 waves = 3-4 waves/SIMD.
// ---------------------------------------------------------------------------
__global__ __launch_bounds__(256, 3) void attn_kernel(const unsigned short* __restrict__ xb,
                                                      const unsigned short* __restrict__ xt,
                                                      unsigned short* __restrict__ ctxt) {
    const int bh = blockIdx.x;
    const int qp = blockIdx.y;       // q-subtile pair index (0..31)
    const int tid = threadIdx.x;
    const int w = tid >> 6;          // 0..3
    const int wql = w & 1;           // which q-subtile of the pair
    const int dh = w >> 1;           // d half (0: d 0-31, 1: d 32-63)
    const int lane = tid & 63;
    const int l31 = lane & 31, hh = lane >> 5;
    const int gs = qp * 2 + wql;     // global q-subtile (0..63)

    const char* xbB = (const char*)(xb + (size_t)bh * 131072);
    const char* xtB = (const char*)(xt + (size_t)bh * 131072);

    // --- Q hoist: B-frags for q-subtile gs ---
    bf16x8 qf[4];
    {
        const char* qbase = xbB + (size_t)gs * 4096 + lane * 16;
        #pragma unroll
        for (int ds = 0; ds < 4; ++ds)
            qf[ds] = *(const bf16x8*)(qbase + ds * 1024);
    }

    // ones B-frag for the row-sum MFMA
    bf16x8 ones;
    #pragma unroll
    for (int i = 0; i < 8; ++i) ones[i] = (short)0x3F80;

    f32x16 acc, accS;
    #pragma unroll
    for (int r = 0; r < 16; ++r) { acc[r] = 0.f; accS[r] = 0.f; }

    const char* ka = xbB + lane * 16;                 // K tile tt: + tt*8192
    const char* va = xtB + dh * 4096 + lane * 16;     // V own-half tile tt: + tt*8192

    for (int tt = 0; tt < 32; ++tt) {
        // --- K frags direct to registers (full tile — S needed in full) ---
        bf16x8 kfa[4], kfb[4];
        #pragma unroll
        for (int ds = 0; ds < 4; ++ds) {
            kfa[ds] = *(const bf16x8*)(ka + ds * 1024);
            kfb[ds] = *(const bf16x8*)(ka + 4096 + ds * 1024);
        }

        // --- QK: S^T[kv][q], two 32-kv subtiles ---
        f32x16 s0, s1;
        #pragma unroll
        for (int r = 0; r < 16; ++r) { s0[r] = 0.f; s1[r] = 0.f; }
        __builtin_amdgcn_s_setprio(1);
        #pragma unroll
        for (int ds = 0; ds < 4; ++ds) {
            s0 = MFMA32(kfa[ds], qf[ds], s0);
            s1 = MFMA32(kfb[ds], qf[ds], s1);
        }
        __builtin_amdgcn_s_setprio(0);

        // --- V frags (own d-half only) — latency hidden under softmax ---
        bf16x8 vf[4];
        #pragma unroll
        for (int ks = 0; ks < 4; ++ks)
            vf[ks] = *(const bf16x8*)(va + ks * 1024);
        ka += 8192;
        va += 8192;

        // --- exp2 in place (lane-local rows, scale pre-folded) ---
        #pragma unroll
        for (int r = 0; r < 16; ++r) {
            s0[r] = __builtin_amdgcn_exp2f(s0[r]);
            s1[r] = __builtin_amdgcn_exp2f(s1[r]);
        }

        // --- pack P -> A-frags via cvt_pk + permlane32_swap (r16-verified) ---
        bf16x8 pa[4];
        #pragma unroll
        for (int ks = 0; ks < 4; ++ks) {
            const int r0 = (ks & 1) * 8;
            unsigned int x0, y0, x1, y1;
            if (ks < 2) {
                x0 = cvtpk(s0[r0 + 0], s0[r0 + 1]);
                y0 = cvtpk(s0[r0 + 4], s0[r0 + 5]);
                x1 = cvtpk(s0[r0 + 2], s0[r0 + 3]);
                y1 = cvtpk(s0[r0 + 6], s0[r0 + 7]);
            } else {
                x0 = cvtpk(s1[r0 + 0], s1[r0 + 1]);
                y0 = cvtpk(s1[r0 + 4], s1[r0 + 5]);
                x1 = cvtpk(s1[r0 + 2], s1[r0 + 3]);
                y1 = cvtpk(s1[r0 + 6], s1[r0 + 7]);
            }
            pl32swap(x0, y0);
            pl32swap(x1, y1);
            union { unsigned int u[4]; bf16x8 v; } pu;
            pu.u[0] = x0; pu.u[1] = x1; pu.u[2] = y0; pu.u[3] = y1;
            pa[ks] = pu.v;
        }

        // --- PV (own d-half) + row-sum on the matrix pipe ---
        __builtin_amdgcn_s_setprio(1);
        #pragma unroll
        for (int ks = 0; ks < 4; ++ks) {
            acc  = MFMA32(pa[ks], vf[ks], acc);
            accS = MFMA32(pa[ks], ones, accS);
        }
        __builtin_amdgcn_s_setprio(0);
    }

    // --- epilogue: accS[r] is the rowsum for exactly acc[r]'s row ---
    const int b = bh >> 4, hd = bh & 15;
    const int mt = b * 16 + (gs >> 2);
    unsigned short* tbase = ctxt + ((size_t)mt * 16 + hd) * 128 * 64;
    const int c8 = dh * 4 + (l31 >> 3), ce = l31 & 7;
    #pragma unroll
    for (int r = 0; r < 16; ++r) {
        const float iv = 1.0f / accS[r];
        const int crow = (r & 3) + 8 * (r >> 2) + 4 * hh;
        const int rr = (gs & 3) * 32 + crow;
        unsigned short* rowp = tbase + rr * 64;
        const int sw = rr & 7;
        rowp[((c8 ^ sw) * 8) + ce] = f2bs(acc[r] * iv);
    }
}

// ---------------------------------------------------------------------------
// Kernel 3: out = ctx @ W^T + b (unchanged).
// ---------------------------------------------------------------------------
__global__ __launch_bounds__(256) void proj_kernel(const unsigned short* __restrict__ ctxt,
                                                   const unsigned short* __restrict__ wbt,
                                                   const float* __restrict__ bias,
                                                   float* __restrict__ out) {
    const int ntb = blockIdx.x;
    const int mtb = blockIdx.y;
    const int tid = threadIdx.x;
    const int w = tid >> 6, lane = tid & 63;
    const int la = lane & 15, quad = lane >> 4;
    const int wm = (w >> 1) * 64, wn = (w & 1) * 64;

    __shared__ __align__(16) unsigned short As[2][8192];
    __shared__ __align__(16) unsigned short Bs[2][8192];

    const unsigned short* abase = ctxt + (size_t)mtb * 16 * 8192;
    const unsigned short* bbase = wbt  + (size_t)ntb * 16 * 8192;

    const int sw0 = ((quad)     ^ (la & 7)) * 8;
    const int sw1 = ((quad + 4) ^ (la & 7)) * 8;

    const f32x4 fzero = {0.f, 0.f, 0.f, 0.f};
    f32x4 acc[4][4];
    #pragma unroll
    for (int i = 0; i < 4; ++i)
        #pragma unroll
        for (int j = 0; j < 4; ++j) acc[i][j] = fzero;

    #pragma unroll
    for (int j = 0; j < 4; ++j) {
        const int fc = j * 256 + tid;
        GLOAD_LDS((const char*)abase + fc * 16, (char*)As[0] + fc * 16);
        GLOAD_LDS((const char*)bbase + fc * 16, (char*)Bs[0] + fc * 16);
    }
    __syncthreads();

    for (int kt = 0; kt < 16; ++kt) {
        if (kt < 15) {
            const char* asrc = (const char*)(abase + (kt + 1) * 8192);
            const char* bsrc = (const char*)(bbase + (kt + 1) * 8192);
            char* adst = (char*)As[(kt + 1) & 1];
            char* bdst = (char*)Bs[(kt + 1) & 1];
            #pragma unroll
            for (int j = 0; j < 4; ++j) {
                const int fc = j * 256 + tid;
                GLOAD_LDS(asrc + fc * 16, adst + fc * 16);
                GLOAD_LDS(bsrc + fc * 16, bdst + fc * 16);
            }
        }

        const unsigned short* Ab = As[kt & 1];
        const unsigned short* Bb = Bs[kt & 1];
        #pragma unroll
        for (int ks2 = 0; ks2 < 2; ++ks2) {
            const int sw = ks2 ? sw1 : sw0;
            bf16x8 af[4], bfr[4];
            #pragma unroll
            for (int mt = 0; mt < 4; ++mt) af[mt]  = *(const bf16x8*)&Ab[(wm + mt * 16 + la) * 64 + sw];
            #pragma unroll
            for (int nt = 0; nt < 4; ++nt) bfr[nt] = *(const bf16x8*)&Bb[(wn + nt * 16 + la) * 64 + sw];
            #pragma unroll
            for (int mt = 0; mt < 4; ++mt)
                #pragma unroll
                for (int nt = 0; nt < 4; ++nt)
                    acc[mt][nt] = __builtin_amdgcn_mfma_f32_16x16x32_bf16(af[mt], bfr[nt], acc[mt][nt], 0, 0, 0);
        }
        __syncthreads();
    }

    const int m0 = mtb * 128, n0 = ntb * 128;
    #pragma unroll
    for (int nt = 0; nt < 4; ++nt) {
        const int n = n0 + wn + nt * 16 + la;
        const float bv = bias[n];
        #pragma unroll
        for (int mt = 0; mt < 4; ++mt)
            #pragma unroll
            for (int r = 0; r < 4; ++r) {
                const int m = m0 + wm + mt * 16 + quad * 4 + r;
                out[(size_t)m * HDIM + n] = acc[mt][nt][r] + bv;
            }
    }
}

// ---------------------------------------------------------------------------
extern "C" void kernel_launch(void* const* d_in, const int* in_sizes, int n_in,
                              void* d_out, int out_size, void* d_ws, size_t ws_size,
                              hipStream_t stream) {
    const float* x    = (const float*)d_in[0];
    const float* W    = (const float*)d_in[1];
    const float* bias = (const float*)d_in[2];
    float* out = (float*)d_out;

    // ws layout (bytes): ctxt 8M | xb 8M | xt 8M | wbt 2M
    unsigned short* ctxt = (unsigned short*)d_ws;
    unsigned short* xbp  = (unsigned short*)((char*)d_ws + ( 8u << 20));
    unsigned short* xtp  = (unsigned short*)((char*)d_ws + (16u << 20));
    unsigned short* wbt  = (unsigned short*)((char*)d_ws + (24u << 20));

    prep_kernel<<<dim3(32, 32), 256, 0, stream>>>(x, W, xbp, xtp, wbt);
    attn_kernel<<<dim3(32, 32), 256, 0, stream>>>(xbp, xtp, ctxt);
    proj_kernel<<<dim3(8, 32), 256, 0, stream>>>(ctxt, wbt, bias, out);
}

// Round 15
// 142.633 us; speedup vs baseline: 1.3288x; 1.1873x over previous
//
#include <hip/hip_runtime.h>
#include <stdint.h>

#define NH     16
#define LSEQ   2048
#define DH     64
#define HDIM   1024
#define BATCH  2

typedef __attribute__((ext_vector_type(8))) short bf16x8;
typedef __attribute__((ext_vector_type(8))) unsigned short u16x8;
typedef __attribute__((ext_vector_type(4))) float f32x4;
typedef __attribute__((ext_vector_type(16))) float f32x16;

// fp32 -> bf16 (RNE)
static __device__ inline unsigned short f2bs(float f) {
    union { float f; uint32_t u; } v; v.f = f;
    uint32_t u = v.u;
    return (unsigned short)((u + 0x7FFFu + ((u >> 16) & 1u)) >> 16);
}

static __device__ inline unsigned int cvtpk(float lo, float hi) {
    unsigned int r;
    asm("v_cvt_pk_bf16_f32 %0, %1, %2" : "=v"(r) : "v"(lo), "v"(hi));
    return r;
}
static __device__ inline void pl32swap(unsigned int &a, unsigned int &b) {
    asm volatile("v_permlane32_swap_b32 %0, %1" : "+v"(a), "+v"(b));
}

#define GLOAD_LDS(gp, lp) \
    __builtin_amdgcn_global_load_lds((const __attribute__((address_space(1))) void*)(gp), \
                                     (__attribute__((address_space(3))) void*)(lp), 16, 0, 0)

#define MFMA32(A, B, C) __builtin_amdgcn_mfma_f32_32x32x16_bf16((A), (B), (C), 0, 0, 0)

// sqrt(0.125 * log2(e)) — folded into xb so (sQ)·(sK) carries the softmax scale
#define QK_SCALE 0.42466083f

// ---------------------------------------------------------------------------
// Kernel 1: prep (unchanged from r17 — verified frag-major layouts).
// ---------------------------------------------------------------------------
__global__ __launch_bounds__(256) void prep_kernel(const float* __restrict__ x,
                                                   const float* __restrict__ W,
                                                   unsigned short* __restrict__ xb,
                                                   unsigned short* __restrict__ xt,
                                                   unsigned short* __restrict__ wbt) {
    const int lt = blockIdx.x, bh = blockIdx.y;
    const int bid = bh * 32 + lt;
    const int t = threadIdx.x;

    if (t < 128) {
        const int gid = bid * 128 + t;
        const int n  = gid >> 7;
        const int kc = gid & 127;
        const float* src = W + (size_t)n * 1024 + kc * 8;
        float4 f0 = *(const float4*)(src);
        float4 f1 = *(const float4*)(src + 4);
        u16x8 v;
        v[0]=f2bs(f0.x); v[1]=f2bs(f0.y); v[2]=f2bs(f0.z); v[3]=f2bs(f0.w);
        v[4]=f2bs(f1.x); v[5]=f2bs(f1.y); v[6]=f2bs(f1.z); v[7]=f2bs(f1.w);
        const int nt = n >> 7, rn = n & 127;
        const int kt = kc >> 3, c = kc & 7;
        *(u16x8*)(wbt + (((size_t)nt * 16 + kt) * 128 + rn) * 64 + ((c ^ (rn & 7)) * 8)) = v;
    }

    const int b = bh >> 4, h = bh & 15;
    const int r = t >> 2, cp = t & 3;

    __shared__ __align__(16) unsigned short Sm[64][72];

    const float* src = x + ((size_t)(b * LSEQ + lt * 64 + r)) * HDIM + h * DH + cp * 16;
    float4 f0 = *(const float4*)(src);
    float4 f1 = *(const float4*)(src + 4);
    float4 f2 = *(const float4*)(src + 8);
    float4 f3 = *(const float4*)(src + 12);
    u16x8 lo, hi;
    lo[0]=f2bs(f0.x); lo[1]=f2bs(f0.y); lo[2]=f2bs(f0.z); lo[3]=f2bs(f0.w);
    lo[4]=f2bs(f1.x); lo[5]=f2bs(f1.y); lo[6]=f2bs(f1.z); lo[7]=f2bs(f1.w);
    hi[0]=f2bs(f2.x); hi[1]=f2bs(f2.y); hi[2]=f2bs(f2.z); hi[3]=f2bs(f2.w);
    hi[4]=f2bs(f3.x); hi[5]=f2bs(f3.y); hi[6]=f2bs(f3.z); hi[7]=f2bs(f3.w);
    u16x8 slo, shi;
    slo[0]=f2bs(f0.x*QK_SCALE); slo[1]=f2bs(f0.y*QK_SCALE); slo[2]=f2bs(f0.z*QK_SCALE); slo[3]=f2bs(f0.w*QK_SCALE);
    slo[4]=f2bs(f1.x*QK_SCALE); slo[5]=f2bs(f1.y*QK_SCALE); slo[6]=f2bs(f1.z*QK_SCALE); slo[7]=f2bs(f1.w*QK_SCALE);
    shi[0]=f2bs(f2.x*QK_SCALE); shi[1]=f2bs(f2.y*QK_SCALE); shi[2]=f2bs(f2.z*QK_SCALE); shi[3]=f2bs(f2.w*QK_SCALE);
    shi[4]=f2bs(f3.x*QK_SCALE); shi[5]=f2bs(f3.y*QK_SCALE); shi[6]=f2bs(f3.z*QK_SCALE); shi[7]=f2bs(f3.w*QK_SCALE);

    {   // xb frag-major: st = lt*2 + (r>>5); ds = cp; lane = hh*32 + (r&31)
        unsigned short* xbase = xb + (size_t)bh * 131072
                              + ((size_t)lt * 2 + (r >> 5)) * 2048 + cp * 512 + (r & 31) * 8;
        *(u16x8*)(xbase)       = slo;   // hh=0 (d = cp*16 + 0..7)
        *(u16x8*)(xbase + 256) = shi;   // hh=1 (d = cp*16 + 8..15)
    }
    *(u16x8*)&Sm[r][cp * 16]     = lo;
    *(u16x8*)&Sm[r][cp * 16 + 8] = hi;
    __syncthreads();

    {   // xt frag-major: tile = lt; side = d>>5; ks = part>>4; lane = hh*32 + (d&31)
        const int d = t >> 2, part = (t & 3) * 16;
        unsigned short* vbase = xt + (size_t)bh * 131072 + (size_t)lt * 4096
                              + (d >> 5) * 2048 + (part >> 4) * 512 + (d & 31) * 8;
        u16x8 g0, g1;
        #pragma unroll
        for (int i = 0; i < 8; ++i) g0[i] = Sm[part + i][d];
        #pragma unroll
        for (int i = 0; i < 8; ++i) g1[i] = Sm[part + 8 + i][d];
        *(u16x8*)(vbase)       = g0;   // kv part..part+7   (hh=0)
        *(u16x8*)(vbase + 256) = g1;   // kv part+8..part+15 (hh=1)
    }
}

// ---------------------------------------------------------------------------
// Kernel 2: flash attention (r17 — measured best, 55.0us): 32x32 MFMA,
// ZERO LDS / ZERO barriers, register-direct frag loads, MFMA ones-trick
// row-sum. At its structural floor (~19 TB/s L1/L2 + dep-chain); 9 probes
// (conflicts, pipelining, TLP, ILP) all null — do not touch.
// grid (32 bh, 16 qt) = 512 blocks, 256 thr (4 waves x 32 q-rows).
// ---------------------------------------------------------------------------
__global__ __launch_bounds__(256, 3) void attn_kernel(const unsigned short* __restrict__ xb,
                                                      const unsigned short* __restrict__ xt,
                                                      unsigned short* __restrict__ ctxt) {
    const int bh = blockIdx.x;
    const int qt = blockIdx.y;
    const int tid = threadIdx.x;
    const int w = tid >> 6, lane = tid & 63;
    const int l31 = lane & 31, hh = lane >> 5;

    const char* xbB = (const char*)(xb + (size_t)bh * 131072);
    const char* xtB = (const char*)(xt + (size_t)bh * 131072);

    // --- Q hoist: B-frags for q-subtile st_q = qt*4 + w ---
    bf16x8 qf[4];
    {
        const char* qbase = xbB + (size_t)(qt * 4 + w) * 4096 + lane * 16;
        #pragma unroll
        for (int ds = 0; ds < 4; ++ds)
            qf[ds] = *(const bf16x8*)(qbase + ds * 1024);
    }

    // ones B-frag for the row-sum MFMA
    bf16x8 ones;
    #pragma unroll
    for (int i = 0; i < 8; ++i) ones[i] = (short)0x3F80;

    f32x16 accA, accB, accS;
    #pragma unroll
    for (int r = 0; r < 16; ++r) { accA[r] = 0.f; accB[r] = 0.f; accS[r] = 0.f; }

    const char* ka = xbB + lane * 16;   // K tile tt: + tt*8192 (+4096 for 2nd subtile)
    const char* va = xtB + lane * 16;   // V tile tt: + tt*8192 (+4096 for side 1)

    for (int tt = 0; tt < 32; ++tt) {
        // --- K frags direct to registers ---
        bf16x8 kfa[4], kfb[4];
        #pragma unroll
        for (int ds = 0; ds < 4; ++ds) {
            kfa[ds] = *(const bf16x8*)(ka + ds * 1024);
            kfb[ds] = *(const bf16x8*)(ka + 4096 + ds * 1024);
        }

        // --- QK: S^T[kv][q], two 32-kv subtiles ---
        f32x16 s0, s1;
        #pragma unroll
        for (int r = 0; r < 16; ++r) { s0[r] = 0.f; s1[r] = 0.f; }
        __builtin_amdgcn_s_setprio(1);
        #pragma unroll
        for (int ds = 0; ds < 4; ++ds) {
            s0 = MFMA32(kfa[ds], qf[ds], s0);
            s1 = MFMA32(kfb[ds], qf[ds], s1);
        }
        __builtin_amdgcn_s_setprio(0);

        // --- V frags direct to registers (latency hidden under softmax) ---
        bf16x8 vfa[4], vfb[4];
        #pragma unroll
        for (int ks = 0; ks < 4; ++ks) {
            vfa[ks] = *(const bf16x8*)(va + ks * 1024);
            vfb[ks] = *(const bf16x8*)(va + 4096 + ks * 1024);
        }
        ka += 8192;
        va += 8192;

        // --- exp2 in place (lane-local softmax rows, scale pre-folded) ---
        #pragma unroll
        for (int r = 0; r < 16; ++r) {
            s0[r] = __builtin_amdgcn_exp2f(s0[r]);
            s1[r] = __builtin_amdgcn_exp2f(s1[r]);
        }

        // --- pack P -> A-frags via cvt_pk + permlane32_swap (r16-verified) ---
        bf16x8 pa[4];
        #pragma unroll
        for (int ks = 0; ks < 4; ++ks) {
            const int r0 = (ks & 1) * 8;
            unsigned int x0, y0, x1, y1;
            if (ks < 2) {
                x0 = cvtpk(s0[r0 + 0], s0[r0 + 1]);
                y0 = cvtpk(s0[r0 + 4], s0[r0 + 5]);
                x1 = cvtpk(s0[r0 + 2], s0[r0 + 3]);
                y1 = cvtpk(s0[r0 + 6], s0[r0 + 7]);
            } else {
                x0 = cvtpk(s1[r0 + 0], s1[r0 + 1]);
                y0 = cvtpk(s1[r0 + 4], s1[r0 + 5]);
                x1 = cvtpk(s1[r0 + 2], s1[r0 + 3]);
                y1 = cvtpk(s1[r0 + 6], s1[r0 + 7]);
            }
            pl32swap(x0, y0);
            pl32swap(x1, y1);
            union { unsigned int u[4]; bf16x8 v; } pu;
            pu.u[0] = x0; pu.u[1] = x1; pu.u[2] = y0; pu.u[3] = y1;
            pa[ks] = pu.v;
        }

        // --- PV + row-sum: O += P.V ; accS += P.1 (matrix pipe, not VALU) ---
        __builtin_amdgcn_s_setprio(1);
        #pragma unroll
        for (int ks = 0; ks < 4; ++ks) {
            accA = MFMA32(pa[ks], vfa[ks], accA);
            accB = MFMA32(pa[ks], vfb[ks], accB);
            accS = MFMA32(pa[ks], ones, accS);
        }
        __builtin_amdgcn_s_setprio(0);
    }

    // --- epilogue: accS[r] is the rowsum for exactly accA[r]/accB[r]'s row ---
    const int b = bh >> 4, hd = bh & 15;
    const int mt = b * 16 + qt;
    unsigned short* tbase = ctxt + ((size_t)mt * 16 + hd) * 128 * 64;
    const int c80 = l31 >> 3, c81 = 4 + (l31 >> 3), ce = l31 & 7;
    #pragma unroll
    for (int r = 0; r < 16; ++r) {
        const float iv = 1.0f / accS[r];
        const int crow = (r & 3) + 8 * (r >> 2) + 4 * hh;
        const int rr = w * 32 + crow;
        unsigned short* rowp = tbase + rr * 64;
        const int sw = rr & 7;
        rowp[((c80 ^ sw) * 8) + ce] = f2bs(accA[r] * iv);
        rowp[((c81 ^ sw) * 8) + ce] = f2bs(accB[r] * iv);
    }
}

// ---------------------------------------------------------------------------
// Kernel 3: out = ctx @ W^T + b. 128x128 tile, BK=64.
// r21: depth-2 prefetch pipeline — 3-buffer LDS ring (96 KB), raw s_barrier,
// counted s_waitcnt vmcnt(8) (never 0 until tail). Removes the 16 fully-
// exposed per-iter vmcnt(0) drains (grid = 1 block/CU: no inter-block
// overlap to hide them). Same discipline as the r15-verified attn pipeline.
// grid (8 n, 32 m), block 256 = 4 waves (2x2 64x64 quadrants).
// ---------------------------------------------------------------------------
__global__ __launch_bounds__(256) void proj_kernel(const unsigned short* __restrict__ ctxt,
                                                   const unsigned short* __restrict__ wbt,
                                                   const float* __restrict__ bias,
                                                   float* __restrict__ out) {
    const int ntb = blockIdx.x;
    const int mtb = blockIdx.y;
    const int tid = threadIdx.x;
    const int w = tid >> 6, lane = tid & 63;
    const int la = lane & 15, quad = lane >> 4;
    const int wm = (w >> 1) * 64, wn = (w & 1) * 64;

    __shared__ __align__(16) unsigned short As[3][8192];
    __shared__ __align__(16) unsigned short Bs[3][8192];

    const unsigned short* abase = ctxt + (size_t)mtb * 16 * 8192;
    const unsigned short* bbase = wbt  + (size_t)ntb * 16 * 8192;

    const int sw0 = ((quad)     ^ (la & 7)) * 8;
    const int sw1 = ((quad + 4) ^ (la & 7)) * 8;

    const f32x4 fzero = {0.f, 0.f, 0.f, 0.f};
    f32x4 acc[4][4];
    #pragma unroll
    for (int i = 0; i < 4; ++i)
        #pragma unroll
        for (int j = 0; j < 4; ++j) acc[i][j] = fzero;

    // prologue: stage kt=0 -> buf0, kt=1 -> buf1 (8 loads each)
    #pragma unroll
    for (int s = 0; s < 2; ++s) {
        const char* asrc = (const char*)(abase + s * 8192);
        const char* bsrc = (const char*)(bbase + s * 8192);
        #pragma unroll
        for (int j = 0; j < 4; ++j) {
            const int fc = j * 256 + tid;
            GLOAD_LDS(asrc + fc * 16, (char*)As[s] + fc * 16);
            GLOAD_LDS(bsrc + fc * 16, (char*)Bs[s] + fc * 16);
        }
    }
    // kt=0's 8 loads landed; kt=1's 8 stay in flight
    asm volatile("s_waitcnt vmcnt(8)" ::: "memory");
    __builtin_amdgcn_s_barrier();

    for (int kt = 0; kt < 16; ++kt) {
        // issue stage(kt+2) into ring slot (kt+2)%3 — slot was last read in
        // iter kt-1, whose end-of-iter barrier all waves have passed.
        if (kt < 14) {
            const int nb = (kt + 2) % 3;
            const char* asrc = (const char*)(abase + (kt + 2) * 8192);
            const char* bsrc = (const char*)(bbase + (kt + 2) * 8192);
            #pragma unroll
            for (int j = 0; j < 4; ++j) {
                const int fc = j * 256 + tid;
                GLOAD_LDS(asrc + fc * 16, (char*)As[nb] + fc * 16);
                GLOAD_LDS(bsrc + fc * 16, (char*)Bs[nb] + fc * 16);
            }
        }

        const unsigned short* Ab = As[kt % 3];
        const unsigned short* Bb = Bs[kt % 3];
        #pragma unroll
        for (int ks2 = 0; ks2 < 2; ++ks2) {
            const int sw = ks2 ? sw1 : sw0;
            bf16x8 af[4], bfr[4];
            #pragma unroll
            for (int mt = 0; mt < 4; ++mt) af[mt]  = *(const bf16x8*)&Ab[(wm + mt * 16 + la) * 64 + sw];
            #pragma unroll
            for (int nt = 0; nt < 4; ++nt) bfr[nt] = *(const bf16x8*)&Bb[(wn + nt * 16 + la) * 64 + sw];
            #pragma unroll
            for (int mt = 0; mt < 4; ++mt)
                #pragma unroll
                for (int nt = 0; nt < 4; ++nt)
                    acc[mt][nt] = __builtin_amdgcn_mfma_f32_16x16x32_bf16(af[mt], bfr[nt], acc[mt][nt], 0, 0, 0);
        }

        // counted wait: kt+1's loads landed; kt+2's stay in flight.
        if (kt < 14) {
            asm volatile("s_waitcnt vmcnt(8)" ::: "memory");
            __builtin_amdgcn_s_barrier();
        } else if (kt == 14) {
            asm volatile("s_waitcnt vmcnt(0)" ::: "memory");
            __builtin_amdgcn_s_barrier();
        }
    }

    const int m0 = mtb * 128, n0 = ntb * 128;
    #pragma unroll
    for (int nt = 0; nt < 4; ++nt) {
        const int n = n0 + wn + nt * 16 + la;
        const float bv = bias[n];
        #pragma unroll
        for (int mt = 0; mt < 4; ++mt)
            #pragma unroll
            for (int r = 0; r < 4; ++r) {
                const int m = m0 + wm + mt * 16 + quad * 4 + r;
                out[(size_t)m * HDIM + n] = acc[mt][nt][r] + bv;
            }
    }
}

// ---------------------------------------------------------------------------
extern "C" void kernel_launch(void* const* d_in, const int* in_sizes, int n_in,
                              void* d_out, int out_size, void* d_ws, size_t ws_size,
                              hipStream_t stream) {
    const float* x    = (const float*)d_in[0];
    const float* W    = (const float*)d_in[1];
    const float* bias = (const float*)d_in[2];
    float* out = (float*)d_out;

    // ws layout (bytes): ctxt 8M | xb 8M | xt 8M | wbt 2M
    unsigned short* ctxt = (unsigned short*)d_ws;
    unsigned short* xbp  = (unsigned short*)((char*)d_ws + ( 8u << 20));
    unsigned short* xtp  = (unsigned short*)((char*)d_ws + (16u << 20));
    unsigned short* wbt  = (unsigned short*)((char*)d_ws + (24u << 20));

    prep_kernel<<<dim3(32, 32), 256, 0, stream>>>(x, W, xbp, xtp, wbt);
    attn_kernel<<<dim3(32, 16), 256, 0, stream>>>(xbp, xtp, ctxt);
    proj_kernel<<<dim3(8, 32), 256, 0, stream>>>(ctxt, wbt, bias, out);
}

// Round 19
// 135.900 us; speedup vs baseline: 1.3946x; 1.0495x over previous
//
#include <hip/hip_runtime.h>
#include <stdint.h>

#define NH     16
#define LSEQ   2048
#define DH     64
#define HDIM   1024
#define BATCH  2

typedef __attribute__((ext_vector_type(8))) short bf16x8;
typedef __attribute__((ext_vector_type(8))) unsigned short u16x8;
typedef __attribute__((ext_vector_type(4))) float f32x4;
typedef __attribute__((ext_vector_type(16))) float f32x16;

// fp32 -> bf16 (RNE)
static __device__ inline unsigned short f2bs(float f) {
    union { float f; uint32_t u; } v; v.f = f;
    uint32_t u = v.u;
    return (unsigned short)((u + 0x7FFFu + ((u >> 16) & 1u)) >> 16);
}

static __device__ inline unsigned int cvtpk(float lo, float hi) {
    unsigned int r;
    asm("v_cvt_pk_bf16_f32 %0, %1, %2" : "=v"(r) : "v"(lo), "v"(hi));
    return r;
}
static __device__ inline void pl32swap(unsigned int &a, unsigned int &b) {
    asm volatile("v_permlane32_swap_b32 %0, %1" : "+v"(a), "+v"(b));
}

#define GLOAD_LDS(gp, lp) \
    __builtin_amdgcn_global_load_lds((const __attribute__((address_space(1))) void*)(gp), \
                                     (__attribute__((address_space(3))) void*)(lp), 16, 0, 0)

#define MFMA32(A, B, C) __builtin_amdgcn_mfma_f32_32x32x16_bf16((A), (B), (C), 0, 0, 0)

// sqrt(0.125 * log2(e)) — folded into xb so (sQ)·(sK) carries the softmax scale
#define QK_SCALE 0.42466083f

// ---------------------------------------------------------------------------
// Kernel 1: prep (unchanged from r17 — verified frag-major layouts).
// ---------------------------------------------------------------------------
__global__ __launch_bounds__(256) void prep_kernel(const float* __restrict__ x,
                                                   const float* __restrict__ W,
                                                   unsigned short* __restrict__ xb,
                                                   unsigned short* __restrict__ xt,
                                                   unsigned short* __restrict__ wbt) {
    const int lt = blockIdx.x, bh = blockIdx.y;
    const int bid = bh * 32 + lt;
    const int t = threadIdx.x;

    if (t < 128) {
        const int gid = bid * 128 + t;
        const int n  = gid >> 7;
        const int kc = gid & 127;
        const float* src = W + (size_t)n * 1024 + kc * 8;
        float4 f0 = *(const float4*)(src);
        float4 f1 = *(const float4*)(src + 4);
        u16x8 v;
        v[0]=f2bs(f0.x); v[1]=f2bs(f0.y); v[2]=f2bs(f0.z); v[3]=f2bs(f0.w);
        v[4]=f2bs(f1.x); v[5]=f2bs(f1.y); v[6]=f2bs(f1.z); v[7]=f2bs(f1.w);
        const int nt = n >> 7, rn = n & 127;
        const int kt = kc >> 3, c = kc & 7;
        *(u16x8*)(wbt + (((size_t)nt * 16 + kt) * 128 + rn) * 64 + ((c ^ (rn & 7)) * 8)) = v;
    }

    const int b = bh >> 4, h = bh & 15;
    const int r = t >> 2, cp = t & 3;

    __shared__ __align__(16) unsigned short Sm[64][72];

    const float* src = x + ((size_t)(b * LSEQ + lt * 64 + r)) * HDIM + h * DH + cp * 16;
    float4 f0 = *(const float4*)(src);
    float4 f1 = *(const float4*)(src + 4);
    float4 f2 = *(const float4*)(src + 8);
    float4 f3 = *(const float4*)(src + 12);
    u16x8 lo, hi;
    lo[0]=f2bs(f0.x); lo[1]=f2bs(f0.y); lo[2]=f2bs(f0.z); lo[3]=f2bs(f0.w);
    lo[4]=f2bs(f1.x); lo[5]=f2bs(f1.y); lo[6]=f2bs(f1.z); lo[7]=f2bs(f1.w);
    hi[0]=f2bs(f2.x); hi[1]=f2bs(f2.y); hi[2]=f2bs(f2.z); hi[3]=f2bs(f2.w);
    hi[4]=f2bs(f3.x); hi[5]=f2bs(f3.y); hi[6]=f2bs(f3.z); hi[7]=f2bs(f3.w);
    u16x8 slo, shi;
    slo[0]=f2bs(f0.x*QK_SCALE); slo[1]=f2bs(f0.y*QK_SCALE); slo[2]=f2bs(f0.z*QK_SCALE); slo[3]=f2bs(f0.w*QK_SCALE);
    slo[4]=f2bs(f1.x*QK_SCALE); slo[5]=f2bs(f1.y*QK_SCALE); slo[6]=f2bs(f1.z*QK_SCALE); slo[7]=f2bs(f1.w*QK_SCALE);
    shi[0]=f2bs(f2.x*QK_SCALE); shi[1]=f2bs(f2.y*QK_SCALE); shi[2]=f2bs(f2.z*QK_SCALE); shi[3]=f2bs(f2.w*QK_SCALE);
    shi[4]=f2bs(f3.x*QK_SCALE); shi[5]=f2bs(f3.y*QK_SCALE); shi[6]=f2bs(f3.z*QK_SCALE); shi[7]=f2bs(f3.w*QK_SCALE);

    {   // xb frag-major: st = lt*2 + (r>>5); ds = cp; lane = hh*32 + (r&31)
        unsigned short* xbase = xb + (size_t)bh * 131072
                              + ((size_t)lt * 2 + (r >> 5)) * 2048 + cp * 512 + (r & 31) * 8;
        *(u16x8*)(xbase)       = slo;   // hh=0 (d = cp*16 + 0..7)
        *(u16x8*)(xbase + 256) = shi;   // hh=1 (d = cp*16 + 8..15)
    }
    *(u16x8*)&Sm[r][cp * 16]     = lo;
    *(u16x8*)&Sm[r][cp * 16 + 8] = hi;
    __syncthreads();

    {   // xt frag-major: tile = lt; side = d>>5; ks = part>>4; lane = hh*32 + (d&31)
        const int d = t >> 2, part = (t & 3) * 16;
        unsigned short* vbase = xt + (size_t)bh * 131072 + (size_t)lt * 4096
                              + (d >> 5) * 2048 + (part >> 4) * 512 + (d & 31) * 8;
        u16x8 g0, g1;
        #pragma unroll
        for (int i = 0; i < 8; ++i) g0[i] = Sm[part + i][d];
        #pragma unroll
        for (int i = 0; i < 8; ++i) g1[i] = Sm[part + 8 + i][d];
        *(u16x8*)(vbase)       = g0;   // kv part..part+7   (hh=0)
        *(u16x8*)(vbase + 256) = g1;   // kv part+8..part+15 (hh=1)
    }
}

// ---------------------------------------------------------------------------
// Kernel 2: flash attention, 32x32 MFMA, r17 compute structure + LDS ring
// staging. Diagnosis: r17's 4 waves each load the SAME 512KB K/V through the
// L1 port (1.07 GB, 76 B/cyc/CU ≈ port-bound, 4096 cyc/iter = measured wall).
// r22 stages each 16KB K+V tile ONCE per block via global_load_lds into a
// 3-slot ring (48 KB); the frag-major layout makes the LDS image a byte-copy,
// so fragment reads are lane*16-contiguous (1024B/instr) = conflict-free
// (what r16 lacked). Counted vmcnt(4), one barrier/iter (r21-verified ring).
// grid (32 bh, 16 qt) = 512 blocks, 256 thr, 2 blocks/CU.
// ---------------------------------------------------------------------------
__global__ __launch_bounds__(256, 2) void attn_kernel(const unsigned short* __restrict__ xb,
                                                      const unsigned short* __restrict__ xt,
                                                      unsigned short* __restrict__ ctxt) {
    const int bh = blockIdx.x;
    const int qt = blockIdx.y;
    const int tid = threadIdx.x;
    const int w = tid >> 6, lane = tid & 63;
    const int l31 = lane & 31, hh = lane >> 5;

    // ring: slot = [K 8KB | V 8KB]
    __shared__ __align__(16) char KVL[3][16384];

    const char* xbB = (const char*)(xb + (size_t)bh * 131072);
    const char* xtB = (const char*)(xt + (size_t)bh * 131072);

    // --- Q hoist: B-frags for q-subtile st_q = qt*4 + w ---
    bf16x8 qf[4];
    {
        const char* qbase = xbB + (size_t)(qt * 4 + w) * 4096 + lane * 16;
        #pragma unroll
        for (int ds = 0; ds < 4; ++ds)
            qf[ds] = *(const bf16x8*)(qbase + ds * 1024);
    }

    // ones B-frag for the row-sum MFMA
    bf16x8 ones;
    #pragma unroll
    for (int i = 0; i < 8; ++i) ones[i] = (short)0x3F80;

    f32x16 accA, accB, accS;
    #pragma unroll
    for (int r = 0; r < 16; ++r) { accA[r] = 0.f; accB[r] = 0.f; accS[r] = 0.f; }

    const int soff = tid * 16;   // 256 thr x 16B = 4KB per GLOAD round

    // stage tile t into ring slot s: 4 GLOADs (K 8KB + V 8KB)
#define STAGE(t, s) { \
        const char* kp_ = xbB + (size_t)(t) * 8192; \
        const char* vp_ = xtB + (size_t)(t) * 8192; \
        GLOAD_LDS(kp_ + soff,        KVL[s] + soff); \
        GLOAD_LDS(kp_ + 4096 + soff, KVL[s] + 4096 + soff); \
        GLOAD_LDS(vp_ + soff,        KVL[s] + 8192 + soff); \
        GLOAD_LDS(vp_ + 4096 + soff, KVL[s] + 12288 + soff); \
    }

    // prologue: tiles 0 and 1
    STAGE(0, 0);
    STAGE(1, 1);
    // tile 0's 4 loads landed; tile 1's 4 stay in flight
    asm volatile("s_waitcnt vmcnt(4)" ::: "memory");
    __builtin_amdgcn_s_barrier();

    for (int tt = 0; tt < 32; ++tt) {
        // issue stage(tt+2) into slot (tt+2)%3 — last read at iter tt-1,
        // all waves passed that iter's barrier.
        if (tt < 30) {
            const int nb = (tt + 2) % 3;
            STAGE(tt + 2, nb);
        }

        const char* kb = KVL[tt % 3] + lane * 16;
        const char* vb = KVL[tt % 3] + 8192 + lane * 16;

        // --- K frags from LDS (contiguous 1024B per instr: conflict-free) ---
        bf16x8 kfa[4], kfb[4];
        #pragma unroll
        for (int ds = 0; ds < 4; ++ds) {
            kfa[ds] = *(const bf16x8*)(kb + ds * 1024);
            kfb[ds] = *(const bf16x8*)(kb + 4096 + ds * 1024);
        }

        // --- QK: S^T[kv][q], two 32-kv subtiles ---
        f32x16 s0, s1;
        #pragma unroll
        for (int r = 0; r < 16; ++r) { s0[r] = 0.f; s1[r] = 0.f; }
        __builtin_amdgcn_s_setprio(1);
        #pragma unroll
        for (int ds = 0; ds < 4; ++ds) {
            s0 = MFMA32(kfa[ds], qf[ds], s0);
            s1 = MFMA32(kfb[ds], qf[ds], s1);
        }
        __builtin_amdgcn_s_setprio(0);

        // --- V frags from LDS (latency hidden under softmax) ---
        bf16x8 vfa[4], vfb[4];
        #pragma unroll
        for (int ks = 0; ks < 4; ++ks) {
            vfa[ks] = *(const bf16x8*)(vb + ks * 1024);
            vfb[ks] = *(const bf16x8*)(vb + 4096 + ks * 1024);
        }

        // --- exp2 in place (lane-local softmax rows, scale pre-folded) ---
        #pragma unroll
        for (int r = 0; r < 16; ++r) {
            s0[r] = __builtin_amdgcn_exp2f(s0[r]);
            s1[r] = __builtin_amdgcn_exp2f(s1[r]);
        }

        // --- pack P -> A-frags via cvt_pk + permlane32_swap (r16-verified) ---
        bf16x8 pa[4];
        #pragma unroll
        for (int ks = 0; ks < 4; ++ks) {
            const int r0 = (ks & 1) * 8;
            unsigned int x0, y0, x1, y1;
            if (ks < 2) {
                x0 = cvtpk(s0[r0 + 0], s0[r0 + 1]);
                y0 = cvtpk(s0[r0 + 4], s0[r0 + 5]);
                x1 = cvtpk(s0[r0 + 2], s0[r0 + 3]);
                y1 = cvtpk(s0[r0 + 6], s0[r0 + 7]);
            } else {
                x0 = cvtpk(s1[r0 + 0], s1[r0 + 1]);
                y0 = cvtpk(s1[r0 + 4], s1[r0 + 5]);
                x1 = cvtpk(s1[r0 + 2], s1[r0 + 3]);
                y1 = cvtpk(s1[r0 + 6], s1[r0 + 7]);
            }
            pl32swap(x0, y0);
            pl32swap(x1, y1);
            union { unsigned int u[4]; bf16x8 v; } pu;
            pu.u[0] = x0; pu.u[1] = x1; pu.u[2] = y0; pu.u[3] = y1;
            pa[ks] = pu.v;
        }

        // --- PV + row-sum: O += P.V ; accS += P.1 (matrix pipe, not VALU) ---
        __builtin_amdgcn_s_setprio(1);
        #pragma unroll
        for (int ks = 0; ks < 4; ++ks) {
            accA = MFMA32(pa[ks], vfa[ks], accA);
            accB = MFMA32(pa[ks], vfb[ks], accB);
            accS = MFMA32(pa[ks], ones, accS);
        }
        __builtin_amdgcn_s_setprio(0);

        // counted wait: tile tt+1's stage landed; tile tt+2's stays in flight.
        if (tt < 30) {
            asm volatile("s_waitcnt vmcnt(4)" ::: "memory");
        } else {
            asm volatile("s_waitcnt vmcnt(0)" ::: "memory");
        }
        __builtin_amdgcn_s_barrier();
    }
#undef STAGE

    // --- epilogue: accS[r] is the rowsum for exactly accA[r]/accB[r]'s row ---
    const int b = bh >> 4, hd = bh & 15;
    const int mt = b * 16 + qt;
    unsigned short* tbase = ctxt + ((size_t)mt * 16 + hd) * 128 * 64;
    const int c80 = l31 >> 3, c81 = 4 + (l31 >> 3), ce = l31 & 7;
    #pragma unroll
    for (int r = 0; r < 16; ++r) {
        const float iv = 1.0f / accS[r];
        const int crow = (r & 3) + 8 * (r >> 2) + 4 * hh;
        const int rr = w * 32 + crow;
        unsigned short* rowp = tbase + rr * 64;
        const int sw = rr & 7;
        rowp[((c80 ^ sw) * 8) + ce] = f2bs(accA[r] * iv);
        rowp[((c81 ^ sw) * 8) + ce] = f2bs(accB[r] * iv);
    }
}

// ---------------------------------------------------------------------------
// Kernel 3: out = ctx @ W^T + b. 128x128 tile, BK=64, 3-buffer ring,
// counted vmcnt(8) (r21 — passed, kept).
// grid (8 n, 32 m), block 256 = 4 waves (2x2 64x64 quadrants).
// ---------------------------------------------------------------------------
__global__ __launch_bounds__(256) void proj_kernel(const unsigned short* __restrict__ ctxt,
                                                   const unsigned short* __restrict__ wbt,
                                                   const float* __restrict__ bias,
                                                   float* __restrict__ out) {
    const int ntb = blockIdx.x;
    const int mtb = blockIdx.y;
    const int tid = threadIdx.x;
    const int w = tid >> 6, lane = tid & 63;
    const int la = lane & 15, quad = lane >> 4;
    const int wm = (w >> 1) * 64, wn = (w & 1) * 64;

    __shared__ __align__(16) unsigned short As[3][8192];
    __shared__ __align__(16) unsigned short Bs[3][8192];

    const unsigned short* abase = ctxt + (size_t)mtb * 16 * 8192;
    const unsigned short* bbase = wbt  + (size_t)ntb * 16 * 8192;

    const int sw0 = ((quad)     ^ (la & 7)) * 8;
    const int sw1 = ((quad + 4) ^ (la & 7)) * 8;

    const f32x4 fzero = {0.f, 0.f, 0.f, 0.f};
    f32x4 acc[4][4];
    #pragma unroll
    for (int i = 0; i < 4; ++i)
        #pragma unroll
        for (int j = 0; j < 4; ++j) acc[i][j] = fzero;

    // prologue: stage kt=0 -> buf0, kt=1 -> buf1 (8 loads each)
    #pragma unroll
    for (int s = 0; s < 2; ++s) {
        const char* asrc = (const char*)(abase + s * 8192);
        const char* bsrc = (const char*)(bbase + s * 8192);
        #pragma unroll
        for (int j = 0; j < 4; ++j) {
            const int fc = j * 256 + tid;
            GLOAD_LDS(asrc + fc * 16, (char*)As[s] + fc * 16);
            GLOAD_LDS(bsrc + fc * 16, (char*)Bs[s] + fc * 16);
        }
    }
    // kt=0's 8 loads landed; kt=1's 8 stay in flight
    asm volatile("s_waitcnt vmcnt(8)" ::: "memory");
    __builtin_amdgcn_s_barrier();

    for (int kt = 0; kt < 16; ++kt) {
        if (kt < 14) {
            const int nb = (kt + 2) % 3;
            const char* asrc = (const char*)(abase + (kt + 2) * 8192);
            const char* bsrc = (const char*)(bbase + (kt + 2) * 8192);
            #pragma unroll
            for (int j = 0; j < 4; ++j) {
                const int fc = j * 256 + tid;
                GLOAD_LDS(asrc + fc * 16, (char*)As[nb] + fc * 16);
                GLOAD_LDS(bsrc + fc * 16, (char*)Bs[nb] + fc * 16);
            }
        }

        const unsigned short* Ab = As[kt % 3];
        const unsigned short* Bb = Bs[kt % 3];
        #pragma unroll
        for (int ks2 = 0; ks2 < 2; ++ks2) {
            const int sw = ks2 ? sw1 : sw0;
            bf16x8 af[4], bfr[4];
            #pragma unroll
            for (int mt = 0; mt < 4; ++mt) af[mt]  = *(const bf16x8*)&Ab[(wm + mt * 16 + la) * 64 + sw];
            #pragma unroll
            for (int nt = 0; nt < 4; ++nt) bfr[nt] = *(const bf16x8*)&Bb[(wn + nt * 16 + la) * 64 + sw];
            #pragma unroll
            for (int mt = 0; mt < 4; ++mt)
                #pragma unroll
                for (int nt = 0; nt < 4; ++nt)
                    acc[mt][nt] = __builtin_amdgcn_mfma_f32_16x16x32_bf16(af[mt], bfr[nt], acc[mt][nt], 0, 0, 0);
        }

        if (kt < 14) {
            asm volatile("s_waitcnt vmcnt(8)" ::: "memory");
            __builtin_amdgcn_s_barrier();
        } else if (kt == 14) {
            asm volatile("s_waitcnt vmcnt(0)" ::: "memory");
            __builtin_amdgcn_s_barrier();
        }
    }

    const int m0 = mtb * 128, n0 = ntb * 128;
    #pragma unroll
    for (int nt = 0; nt < 4; ++nt) {
        const int n = n0 + wn + nt * 16 + la;
        const float bv = bias[n];
        #pragma unroll
        for (int mt = 0; mt < 4; ++mt)
            #pragma unroll
            for (int r = 0; r < 4; ++r) {
                const int m = m0 + wm + mt * 16 + quad * 4 + r;
                out[(size_t)m * HDIM + n] = acc[mt][nt][r] + bv;
            }
    }
}

// ---------------------------------------------------------------------------
extern "C" void kernel_launch(void* const* d_in, const int* in_sizes, int n_in,
                              void* d_out, int out_size, void* d_ws, size_t ws_size,
                              hipStream_t stream) {
    const float* x    = (const float*)d_in[0];
    const float* W    = (const float*)d_in[1];
    const float* bias = (const float*)d_in[2];
    float* out = (float*)d_out;

    // ws layout (bytes): ctxt 8M | xb 8M | xt 8M | wbt 2M
    unsigned short* ctxt = (unsigned short*)d_ws;
    unsigned short* xbp  = (unsigned short*)((char*)d_ws + ( 8u << 20));
    unsigned short* xtp  = (unsigned short*)((char*)d_ws + (16u << 20));
    unsigned short* wbt  = (unsigned short*)((char*)d_ws + (24u << 20));

    prep_kernel<<<dim3(32, 32), 256, 0, stream>>>(x, W, xbp, xtp, wbt);
    attn_kernel<<<dim3(32, 16), 256, 0, stream>>>(xbp, xtp, ctxt);
    proj_kernel<<<dim3(8, 32), 256, 0, stream>>>(ctxt, wbt, bias, out);
}